// Round 1
// baseline (432.253 us; speedup 1.0000x reference)
//
#include <hip/hip_runtime.h>
#include <math.h>

// MultiEmbodimentActionEncoder B=64,T=64,A=64,H=1024,C=16
// R5: barrier-free K-loop. R4 was latency-bound: 272 blocks -> ~1 wave/SIMD
// (Occupancy 12%) and __syncthreads drained vmcnt(0) every K-step
// (MfmaUtil 6.5%, HBM 15%). Changes:
//  - wave-private W slabs (32k x 32n fp32, XOR-swizzled), global_load_lds
//    staged, 3 buffers; NO __syncthreads in K-loop; counted s_waitcnt vmcnt(N)
//    keeps 2 W-tiles + next A-frags in flight per wave (in-order vmem return).
//  - A-fragments prefetched 1 K-step ahead via raw global_load_dwordx4 asm.
//  - wave tile M128xN32 (8 mt x 2 nt); no inter-wave data sharing.
//  - lgkmcnt(0) at body top = WAR fence for slab reuse; sched_barrier(0)
//    after vmcnt pins packs/MFMA below the wait (rule #18).
//  - tau (sinusoidal) fused into GEMM1 epilogue (4 kernels -> 3).
//  - v_cvt_pk_bf16_f32 for f32->bf16x2 packing.

typedef short bf16x8 __attribute__((ext_vector_type(8)));
typedef float floatx4 __attribute__((ext_vector_type(4)));

__device__ inline short f2bf(float f) {
  union { float f; unsigned u; } v; v.f = f;
  unsigned u = v.u;
  return (short)(((u + 0x7fffu + ((u >> 16) & 1u)) >> 16) & 0xffffu);
}

// v_cvt_pk_bf16_f32: dst.lo = bf16(a), dst.hi = bf16(b) (RTNE)
__device__ __forceinline__ unsigned cvtpk(float a, float b) {
  unsigned r;
  asm("v_cvt_pk_bf16_f32 %0, %1, %2" : "=v"(r) : "v"(a), "v"(b));
  return r;
}

#if __has_builtin(__builtin_amdgcn_global_load_lds)
#define ASYNC_LDS 1
__device__ __forceinline__ void async16(const float* g, float* lds) {
  __builtin_amdgcn_global_load_lds(
      (const __attribute__((address_space(1))) unsigned int*)g,
      (__attribute__((address_space(3))) unsigned int*)lds, 16, 0, 0);
}
#else
#define ASYNC_LDS 0
__device__ __forceinline__ void async16(const float* g, float* lds) {
  *(floatx4*)lds = *(const floatx4*)g;   // sync fallback
}
#endif

__device__ __forceinline__ void gload16(floatx4& d, const void* p) {
  asm volatile("global_load_dwordx4 %0, %1, off" : "=v"(d) : "v"(p) : "memory");
}
template<int N> __device__ __forceinline__ void vm_wait() {
  asm volatile("s_waitcnt vmcnt(%0)" :: "n"(N) : "memory");
}
__device__ __forceinline__ void lgkm0() {
  asm volatile("s_waitcnt lgkmcnt(0)" ::: "memory");
}

// One K-step. Issue order (all volatile/side-effecting => pinned):
//   lgkm0 (WAR fence) ; A(kt+1)->AOUT ; stage(kt+2)->bs ; vmcnt(VMX) ;
//   sched_barrier ; pack+ds_read+16 MFMA on (bc, AIN) ; rotate buffers.
// Steady-state queue at the wait: st(kt+1)[4] + A(kt+1)[AOPS] + st(kt+2)[4]
// may stay outstanding => VM_MAIN = 8+AOPS guarantees st(kt)+A(kt) landed.
#define KBODY(VMX, LOADA, DOSTAGE, AIN, AOUT)                                  \
  {                                                                            \
    lgkm0();                                                                   \
    if (LOADA) {                                                               \
      _Pragma("unroll")                                                        \
      for (int mt = 0; mt < 8; ++mt) {                                         \
        const char* p = arow[mt] + aoff;                                       \
        if constexpr (A_F32) {                                                 \
          gload16(AOUT[2 * mt], p); gload16(AOUT[2 * mt + 1], p + 16);         \
        } else {                                                               \
          gload16(AOUT[mt], p);                                                \
        }                                                                      \
      }                                                                        \
      aoff += 32 * AB;                                                         \
    }                                                                          \
    if (DOSTAGE) {                                                             \
      _Pragma("unroll")                                                        \
      for (int i = 0; i < 4; ++i)                                              \
        async16((const float*)(wbp + goff[i]), bs + i * 256);                  \
      wbp += 32 * 1024 * 4;                                                    \
    }                                                                          \
    vm_wait<VMX>();                                                            \
    __builtin_amdgcn_sched_barrier(0);                                         \
    bf16x8 af[8];                                                              \
    _Pragma("unroll")                                                          \
    for (int mt = 0; mt < 8; ++mt) {                                           \
      if constexpr (A_F32) {                                                   \
        union { bf16x8 v; unsigned u[4]; } t;                                  \
        floatx4 x0 = AIN[2 * mt], x1 = AIN[2 * mt + 1];                        \
        t.u[0] = cvtpk(x0[0], x0[1]); t.u[1] = cvtpk(x0[2], x0[3]);            \
        t.u[2] = cvtpk(x1[0], x1[1]); t.u[3] = cvtpk(x1[2], x1[3]);            \
        af[mt] = t.v;                                                          \
      } else {                                                                 \
        union { floatx4 f; bf16x8 v; } t; t.f = AIN[mt]; af[mt] = t.v;         \
      }                                                                        \
    }                                                                          \
    _Pragma("unroll")                                                          \
    for (int nt = 0; nt < 2; ++nt) {                                           \
      const float* fp = bc + quad * 256 + ((nt * 16 + l16) ^ (quad << 3));     \
      float f[8];                                                              \
      _Pragma("unroll")                                                        \
      for (int j = 0; j < 8; ++j) f[j] = fp[j * 32];                           \
      union { bf16x8 v; unsigned u[4]; } bb;                                   \
      _Pragma("unroll")                                                        \
      for (int j = 0; j < 4; ++j) bb.u[j] = cvtpk(f[2 * j], f[2 * j + 1]);     \
      _Pragma("unroll")                                                        \
      for (int mt = 0; mt < 8; ++mt)                                           \
        acc[mt][nt] = __builtin_amdgcn_mfma_f32_16x16x32_bf16(                 \
            af[mt], bb.v, acc[mt][nt], 0, 0, 0);                               \
    }                                                                          \
    { float* t_ = bc; bc = bn; bn = bs; bs = t_; }                             \
  }

template<int K, bool A_F32, bool SWISH, bool OUT_BF16, bool TAU>
__global__ __launch_bounds__(256, 2) void gemm_kernel(
    const void* __restrict__ Aall, int lda,
    const float* __restrict__ Wall,   // (16, K, 1024)
    const float* __restrict__ bias,   // (16, 1024)
    const int* __restrict__ cat_ids,
    void* __restrict__ Out, int ldo,
    const int* __restrict__ ts)
{
  constexpr int NCOL = 1024;
  constexpr int KT = K / 32;
  constexpr int AB = A_F32 ? 4 : 2;      // A bytes/elem
  constexpr int AOPS = A_F32 ? 16 : 8;   // A vmem ops per K-step
#if ASYNC_LDS
  constexpr int VM_MAIN = 8 + AOPS;      // st(kt+1)+st(kt+2) + A(kt+1)
  constexpr int VM_T1   = 4 + AOPS;      // st(KT-1) + A(KT-1)
#else
  constexpr int VM_MAIN = AOPS;          // fallback stages drain synchronously
  constexpr int VM_T1   = AOPS;
#endif
  static_assert(KT >= 2 && ((KT - 2) % 2 == 0), "K must be a multiple of 64");
  (void)ts;

  __shared__ float slabs[4][3][1024];    // 4 waves x 3 bufs x 4 KiB
  __shared__ int s_b[80], s_c[80], s_np;

  const int tid = threadIdx.x;
  if (tid < 80) { s_b[tid] = -1; s_c[tid] = 0; }
  __syncthreads();
  if (tid < 64) {                        // wave 0: padded counting sort
    const int myc = cat_ids[tid];
    int rank = 0, pst = 0, tot = 0;
    #pragma unroll
    for (int cc = 0; cc < 16; ++cc) {
      unsigned long long m = __ballot(myc == cc);
      const int cnt = __popcll(m);
      const int pc  = 2 * ((cnt + 1) >> 1);     // pad to even
      if (cc < myc)  pst += pc;
      if (cc == myc) rank = __popcll(m & ((1ull << tid) - 1ull));
      tot += pc;
    }
    const int slot = pst + rank;
    s_b[slot] = tid;
    s_c[slot] = myc;
    if (tid == 0) s_np = tot >> 1;
  }
  __syncthreads();                       // last barrier in the kernel

  const int e = blockIdx.y;
  if (e >= s_np) return;
  const int b0v = s_b[2 * e];
  int b1 = s_b[2 * e + 1];
  const int c = s_c[2 * e];
  const bool st1 = (b1 >= 0);
  if (!st1) b1 = b0v;                    // dummy: duplicate rows, mask store

  const int wave = tid >> 6, lane = tid & 63;
  const int quad = lane >> 4, l16 = lane & 15;
  const int ns = blockIdx.x * 128;
  const int wcol = ns + wave * 32;       // this wave's private 32 cols

  // A row pointers: every wave covers all 128 pair rows (8 x 16).
  const char* arow[8];
  #pragma unroll
  for (int mt = 0; mt < 8; ++mt) {
    const int pr = mt * 16 + l16;
    const int batch = (pr < 64) ? b0v : b1;
    const int row = batch * 64 + (pr & 63);
    arow[mt] = (const char*)Aall + (size_t)row * lda * AB;
  }

  // Swizzled W slab: LDS float L(k,cl) = k*32 + (cl ^ ((k>>3)<<3)).
  // global_load_lds writes linearly (slot s = call*64+lane at byte s*16), so
  // the inverse swizzle is applied to the per-lane GLOBAL source address:
  // slot s holds k=s>>3, cols cl0..cl0+3 with cl0 = ((s&7)<<2) ^ ((s>>6)<<3).
  int goff[4];
  #pragma unroll
  for (int i = 0; i < 4; ++i) {
    const int s  = i * 64 + lane;
    const int k  = s >> 3;
    const int c0 = ((s & 7) << 2) ^ ((s >> 6) << 3);
    goff[i] = (k * NCOL + c0) * 4;
  }

  float* const sl0 = &slabs[wave][0][0];
  float* const sl1 = &slabs[wave][1][0];
  float* const sl2 = &slabs[wave][2][0];
  float *bc = sl0, *bn = sl1, *bs = sl2;

  const char* wbp = (const char*)(Wall + (size_t)c * K * NCOL + wcol);

  floatx4 aA[A_F32 ? 16 : 8], aB[A_F32 ? 16 : 8];
  const int aq = quad * 8 * AB;

  // Prologue: A(0) -> aA, stage k-tiles 0 and 1.
  #pragma unroll
  for (int mt = 0; mt < 8; ++mt) {
    const char* p = arow[mt] + aq;
    if constexpr (A_F32) { gload16(aA[2 * mt], p); gload16(aA[2 * mt + 1], p + 16); }
    else                 { gload16(aA[mt], p); }
  }
  #pragma unroll
  for (int i = 0; i < 4; ++i) async16((const float*)(wbp + goff[i]), sl0 + i * 256);
  wbp += 32 * NCOL * 4;
  #pragma unroll
  for (int i = 0; i < 4; ++i) async16((const float*)(wbp + goff[i]), sl1 + i * 256);
  wbp += 32 * NCOL * 4;

  int aoff = aq + 32 * AB;               // next A offset = k-tile 1

  floatx4 acc[8][2];
  #pragma unroll
  for (int mt = 0; mt < 8; ++mt)
    #pragma unroll
    for (int nt = 0; nt < 2; ++nt)
      acc[mt][nt] = (floatx4){0.f, 0.f, 0.f, 0.f};

  // Main loop: KT-2 steps (even), ping-pong A buffers.
  for (int kt = 0; kt + 2 < KT; kt += 2) {
    KBODY(VM_MAIN, true, true, aA, aB);
    KBODY(VM_MAIN, true, true, aB, aA);
  }
  // Tail kt = KT-2: load A(KT-1), no stage.
  KBODY(VM_T1, true, false, aA, aB);
  // Tail kt = KT-1: drain everything.
  KBODY(0, false, false, aB, aA);

  // Epilogue. C/D: row = quad*4 + r, col = l16 (within 16x16 tile).
  #pragma unroll
  for (int nt = 0; nt < 2; ++nt) {
    const int col = wcol + nt * 16 + l16;
    const float bv = bias[(size_t)c * NCOL + col];
    #pragma unroll
    for (int mt = 0; mt < 8; ++mt) {
      const int prb = mt * 16 + quad * 4;
      const int batch = (prb < 64) ? b0v : b1;
      const bool do_store = (prb < 64) || st1;
      #pragma unroll
      for (int r = 0; r < 4; ++r) {
        const int row = batch * 64 + ((prb + r) & 63);
        float v = acc[mt][nt][r] + bv;
        if constexpr (SWISH) v = v / (1.f + __expf(-v));
        if (do_store) {
          if constexpr (OUT_BF16)
            ((short*)Out)[(size_t)row * ldo + col] = f2bf(v);
          else
            ((float*)Out)[(size_t)row * ldo + col] = v;
        }
      }
    }
  }

  // Fused tau: per batch a single 1024-vector (timestep const across T),
  // broadcast into x's right half (cols 1024..2047), rows of this pair.
  if constexpr (TAU) {
    const float t0  = (float)ts[b0v];
    const float t1v = (float)ts[b1];
    const int ic = ns + (tid & 127);       // tau col in [0,1024)
    const int hi = ic & 511;
    const float ef = __expf(-(float)hi * 0.017988946039015980f); // ln(1e4)/512
    float v0, v1;
    if (ic < 512) { v0 = sinf(t0 * ef); v1 = sinf(t1v * ef); }
    else          { v0 = cosf(t0 * ef); v1 = cosf(t1v * ef); }
    const short q0 = f2bf(v0), q1 = f2bf(v1);
    short* xp = (short*)Out;
    const int r0 = tid >> 7;               // row parity: 2 threads per col
    #pragma unroll 4
    for (int rr = 0; rr < 32; ++rr) {
      const int rl = r0 + 2 * rr;
      xp[(size_t)(b0v * 64 + rl) * ldo + 1024 + ic] = q0;
      if (st1) xp[(size_t)(b1 * 64 + rl) * ldo + 1024 + ic] = q1;
    }
  }
}

extern "C" void kernel_launch(void* const* d_in, const int* in_sizes, int n_in,
                              void* d_out, int out_size, void* d_ws, size_t ws_size,
                              hipStream_t stream) {
  const float* actions   = (const float*)d_in[0];
  const int*   timesteps = (const int*)  d_in[1];
  const int*   cat_ids   = (const int*)  d_in[2];
  const float* W1 = (const float*)d_in[3];
  const float* B1 = (const float*)d_in[4];
  const float* W2 = (const float*)d_in[5];
  const float* B2 = (const float*)d_in[6];
  const float* W3 = (const float*)d_in[7];
  const float* B3 = (const float*)d_in[8];

  short* x = (short*)d_ws;                     // (4096, 2048) bf16 = 16 MiB
  short* h = x + (size_t)64 * 64 * 2048;       // (4096, 1024) bf16 =  8 MiB

  dim3 grid(8, 40), blk(256);

  // GEMM1 (K=64, fp32 A) + fused tau -> x
  gemm_kernel<64, true, false, true, true><<<grid, blk, 0, stream>>>(
      (const void*)actions, 64, W1, B1, cat_ids, (void*)x, 2048, timesteps);
  // GEMM2 (K=2048) + swish -> h
  gemm_kernel<2048, false, true, true, false><<<grid, blk, 0, stream>>>(
      (const void*)x, 2048, W2, B2, cat_ids, (void*)h, 1024, nullptr);
  // GEMM3 (K=1024) -> out (fp32)
  gemm_kernel<1024, false, false, false, false><<<grid, blk, 0, stream>>>(
      (const void*)h, 1024, W3, B3, cat_ids, d_out, 1024, nullptr);
}

// Round 2
// 406.759 us; speedup vs baseline: 1.0627x; 1.0627x over previous
//
#include <hip/hip_runtime.h>
#include <math.h>

// MultiEmbodimentActionEncoder B=64,T=64,A=64,H=1024,C=16
// R6: register-direct W, zero LDS in the K-loop.
// R5 post-mortem: mixing global_load_lds (compiler-tracked) with C-level
// ds_read made hipcc inject s_waitcnt vmcnt(0) before the slab reads ->
// full drain every K-step (VALUBusy 5.8%, MfmaUtil 4.9%); plus the XOR
// swizzle was 2-way-conflicted per 32-lane phase (2.49M conflict cycles).
// Fix: the per-wave W tile (32k x 32n fp32 = 4KB) fits in registers.
//  - W: 16x global_load_dword (SGPR base + per-lane voffset, offset: imm
//    for the second 16-col group), double-buffered in VGPRs (depth 2).
//  - A: 8x global_load_dwordx4 (bf16) / 16x (fp32), depth 1.
//  - ALL loads are inline asm => compiler tracks nothing, vmcnt is ours.
//    Invariant entering step s's wait: [W(s):16, A(s):AOPS, W(s+1):16]
//    oldest-first; vm_wait<16> drains exactly W(s)+A(s) (in-order return).
//  - sched_barrier(0) after the wait (rule #18: consumers must not hoist
//    above an asm waitcnt) and after the cvt block (pin WAR on buffers).
//  - block=128 (2 waves, wave tile M128xN32), grid(16,40) -> 640 blocks,
//    ~5 waves/CU, A re-read x16 (L3-absorbed).
//  - tau fused in GEMM1 epilogue; v_cvt_pk_bf16_f32 packing.

typedef short bf16x8 __attribute__((ext_vector_type(8)));
typedef float floatx4 __attribute__((ext_vector_type(4)));

__device__ inline short f2bf(float f) {
  union { float f; unsigned u; } v; v.f = f;
  unsigned u = v.u;
  return (short)(((u + 0x7fffu + ((u >> 16) & 1u)) >> 16) & 0xffffu);
}

// v_cvt_pk_bf16_f32: dst.lo = bf16(a), dst.hi = bf16(b) (RTNE)
__device__ __forceinline__ unsigned cvtpk(float a, float b) {
  unsigned r;
  asm("v_cvt_pk_bf16_f32 %0, %1, %2" : "=v"(r) : "v"(a), "v"(b));
  return r;
}

template<int IMM>
__device__ __forceinline__ void gdw(float& d, unsigned voff, unsigned long long base) {
  asm volatile("global_load_dword %0, %1, %2 offset:%3"
               : "=v"(d) : "v"(voff), "s"(base), "n"(IMM) : "memory");
}
template<int IMM>
__device__ __forceinline__ void gdx4(floatx4& d, unsigned voff, unsigned long long base) {
  asm volatile("global_load_dwordx4 %0, %1, %2 offset:%3"
               : "=v"(d) : "v"(voff), "s"(base), "n"(IMM) : "memory");
}
template<int N>
__device__ __forceinline__ void vm_wait() {
  asm volatile("s_waitcnt vmcnt(%0)" :: "n"(N) : "memory");
}

// Issue one 32k x 32n W tile into 16 scalar f32 regs:
// WBUF[nt*8+j] = W[k = quad*8+j][col = wcol + nt*16 + l16]
#define ISSUE_W(WBUF) do {                                                   \
    _Pragma("unroll")                                                        \
    for (int j = 0; j < 8; ++j) {                                            \
      gdw<0 >(WBUF[j],     vW[j], Wq);                                       \
      gdw<64>(WBUF[8 + j], vW[j], Wq);                                       \
    }                                                                        \
    Wq += 32ull * 1024 * 4;                                                  \
  } while (0)

// Issue the next A k-slice (8 rows-of-16 x 32k per wave).
#define ISSUE_A(ABUF) do {                                                   \
    _Pragma("unroll")                                                        \
    for (int mt = 0; mt < 8; ++mt) {                                         \
      if constexpr (A_F32) {                                                 \
        gdx4<0 >(ABUF[2 * mt],     vA[mt], Aq);                              \
        gdx4<16>(ABUF[2 * mt + 1], vA[mt], Aq);                              \
      } else {                                                               \
        gdx4<0>(ABUF[mt], vA[mt], Aq);                                       \
      }                                                                      \
    }                                                                        \
    Aq += 32ull * AB;                                                        \
  } while (0)

// One K-step: wait{W(s),A(s)} -> cvt -> issue A(s+1), W(s+2) -> 16 MFMA.
#define KSTEP(VM, AIN, AOUT, WIN, DO_A, DO_W) do {                           \
    vm_wait<VM>();                                                           \
    __builtin_amdgcn_sched_barrier(0);                                       \
    union { bf16x8 v; unsigned u[4]; } wb0, wb1;                             \
    _Pragma("unroll")                                                        \
    for (int jj = 0; jj < 4; ++jj) {                                         \
      wb0.u[jj] = cvtpk(WIN[2 * jj],     WIN[2 * jj + 1]);                   \
      wb1.u[jj] = cvtpk(WIN[8 + 2 * jj], WIN[8 + 2 * jj + 1]);               \
    }                                                                        \
    bf16x8 af[8];                                                            \
    _Pragma("unroll")                                                        \
    for (int mt = 0; mt < 8; ++mt) {                                         \
      if constexpr (A_F32) {                                                 \
        union { bf16x8 v; unsigned u[4]; } t;                                \
        floatx4 x0 = AIN[2 * mt], x1 = AIN[2 * mt + 1];                      \
        t.u[0] = cvtpk(x0[0], x0[1]); t.u[1] = cvtpk(x0[2], x0[3]);          \
        t.u[2] = cvtpk(x1[0], x1[1]); t.u[3] = cvtpk(x1[2], x1[3]);          \
        af[mt] = t.v;                                                        \
      } else {                                                               \
        union { floatx4 f; bf16x8 v; } t; t.f = AIN[mt]; af[mt] = t.v;       \
      }                                                                      \
    }                                                                        \
    __builtin_amdgcn_sched_barrier(0);                                       \
    if (DO_A) ISSUE_A(AOUT);                                                 \
    if (DO_W) ISSUE_W(WIN);                                                  \
    _Pragma("unroll")                                                        \
    for (int mt = 0; mt < 8; ++mt) {                                         \
      acc[mt][0] = __builtin_amdgcn_mfma_f32_16x16x32_bf16(af[mt], wb0.v, acc[mt][0], 0, 0, 0); \
      acc[mt][1] = __builtin_amdgcn_mfma_f32_16x16x32_bf16(af[mt], wb1.v, acc[mt][1], 0, 0, 0); \
    }                                                                        \
  } while (0)

template<int K, bool A_F32, bool SWISH, bool OUT_BF16, bool TAU>
__global__ __launch_bounds__(128, 2) void gemm_kernel(
    const void* __restrict__ Aall, int lda,
    const float* __restrict__ Wall,   // (16, K, 1024)
    const float* __restrict__ bias,   // (16, 1024)
    const int* __restrict__ cat_ids,
    void* __restrict__ Out, int ldo,
    const int* __restrict__ ts)
{
  constexpr int NCOL = 1024;
  constexpr int KT = K / 32;
  constexpr int AB = A_F32 ? 4 : 2;      // A bytes/elem
  static_assert(KT >= 2 && ((KT - 2) % 2 == 0), "K must be multiple of 64");
  (void)ts;

  __shared__ int s_b[80], s_c[80], s_np;

  const int tid = threadIdx.x;
  if (tid < 80) { s_b[tid] = -1; s_c[tid] = 0; }
  __syncthreads();
  if (tid < 64) {                        // wave 0: padded counting sort
    const int myc = cat_ids[tid];
    int rank = 0, pst = 0, tot = 0;
    #pragma unroll
    for (int cc = 0; cc < 16; ++cc) {
      unsigned long long m = __ballot(myc == cc);
      const int cnt = __popcll(m);
      const int pc  = 2 * ((cnt + 1) >> 1);     // pad to even
      if (cc < myc)  pst += pc;
      if (cc == myc) rank = __popcll(m & ((1ull << tid) - 1ull));
      tot += pc;
    }
    const int slot = pst + rank;
    s_b[slot] = tid;
    s_c[slot] = myc;
    if (tid == 0) s_np = tot >> 1;
  }
  __syncthreads();                       // last block-wide barrier

  const int e = blockIdx.y;
  if (e >= s_np) return;
  const int b0v = __builtin_amdgcn_readfirstlane(s_b[2 * e]);
  int b1        = __builtin_amdgcn_readfirstlane(s_b[2 * e + 1]);
  const int c   = __builtin_amdgcn_readfirstlane(s_c[2 * e]);
  const bool st1 = (b1 >= 0);
  if (!st1) b1 = b0v;                    // dummy: duplicate rows, mask store

  const int wave = tid >> 6, lane = tid & 63;
  const int quad = lane >> 4, l16 = lane & 15;
  const int ns = blockIdx.x * 64;
  const int wcol = ns + wave * 32;       // this wave's private 32 cols

  // Wave-uniform scalar bases (readfirstlane => SGPR; c*K*NCOL*4 < 2^31).
  const unsigned wqoff = (unsigned)__builtin_amdgcn_readfirstlane(
      (int)(((unsigned)c * (unsigned)K * NCOL + (unsigned)wcol) * 4u));
  unsigned long long Wq = (unsigned long long)Wall + wqoff;
  unsigned long long Aq = (unsigned long long)Aall;

  // Per-lane voffsets (loop-invariant).
  unsigned vW[8];
  #pragma unroll
  for (int j = 0; j < 8; ++j)
    vW[j] = (unsigned)((quad * 8 + j) * (NCOL * 4) + l16 * 4);

  unsigned vA[8];
  #pragma unroll
  for (int mt = 0; mt < 8; ++mt) {
    const int pr = mt * 16 + l16;
    const int batch = (pr < 64) ? b0v : b1;
    const int row = batch * 64 + (pr & 63);
    vA[mt] = (unsigned)(row * lda * AB + quad * 8 * AB);
  }

  float wA[16], wB[16];
  floatx4 aBuf0[A_F32 ? 16 : 8];
  floatx4 aBuf1[A_F32 ? 1 : 8];          // unused in the f32 path

  floatx4 acc[8][2];
  #pragma unroll
  for (int mt = 0; mt < 8; ++mt) {
    acc[mt][0] = (floatx4){0.f, 0.f, 0.f, 0.f};
    acc[mt][1] = (floatx4){0.f, 0.f, 0.f, 0.f};
  }

  // Prologue: W(0), A(0), W(1) — this order makes the steady-state
  // invariant hold from step 0.
  ISSUE_W(wA);
  ISSUE_A(aBuf0);
  ISSUE_W(wB);

  if constexpr (A_F32) {                 // single A buffer (cvt frees it)
    #pragma unroll 1
    for (int s = 0; s + 2 < KT; s += 2) {
      KSTEP(16, aBuf0, aBuf0, wA, true, true);
      KSTEP(16, aBuf0, aBuf0, wB, true, true);
    }
    KSTEP(16, aBuf0, aBuf0, wA, true, false);
    KSTEP(0,  aBuf0, aBuf0, wB, false, false);
  } else {                               // ping-pong A buffers
    #pragma unroll 1
    for (int s = 0; s + 2 < KT; s += 2) {
      KSTEP(16, aBuf0, aBuf1, wA, true, true);
      KSTEP(16, aBuf1, aBuf0, wB, true, true);
    }
    KSTEP(16, aBuf0, aBuf1, wA, true, false);
    KSTEP(0,  aBuf1, aBuf1, wB, false, false);
  }

  // Epilogue. C/D: row = quad*4 + r, col = l16 (within 16x16 tile).
  #pragma unroll
  for (int nt = 0; nt < 2; ++nt) {
    const int col = wcol + nt * 16 + l16;
    const float bv = bias[(size_t)c * NCOL + col];
    #pragma unroll
    for (int mt = 0; mt < 8; ++mt) {
      const int prb = mt * 16 + quad * 4;
      const int batch = (prb < 64) ? b0v : b1;
      const bool do_store = (prb < 64) || st1;
      #pragma unroll
      for (int r = 0; r < 4; ++r) {
        const int row = batch * 64 + ((prb + r) & 63);
        float v = acc[mt][nt][r] + bv;
        if constexpr (SWISH) v = v / (1.f + __expf(-v));
        if (do_store) {
          if constexpr (OUT_BF16)
            ((short*)Out)[(size_t)row * ldo + col] = f2bf(v);
          else
            ((float*)Out)[(size_t)row * ldo + col] = v;
        }
      }
    }
  }

  // Fused tau: per batch one 1024-vector (timestep const across T),
  // broadcast into x's right half. Block covers cols ns..ns+63.
  if constexpr (TAU) {
    const float t0  = (float)ts[b0v];
    const float t1v = (float)ts[b1];
    const int ic = ns + (tid & 63);        // tau col in [0,1024)
    const int hi = ic & 511;
    const float ef = __expf(-(float)hi * 0.017988946039015980f); // ln(1e4)/512
    float v0, v1;
    if (ic < 512) { v0 = sinf(t0 * ef); v1 = sinf(t1v * ef); }
    else          { v0 = cosf(t0 * ef); v1 = cosf(t1v * ef); }
    const short q0 = f2bf(v0), q1 = f2bf(v1);
    short* xp = (short*)Out;
    const int r0 = tid >> 6;               // 2 threads per col -> 64 rows
    #pragma unroll 4
    for (int rr = 0; rr < 32; ++rr) {
      const int rl = r0 + 2 * rr;
      xp[(size_t)(b0v * 64 + rl) * ldo + 1024 + ic] = q0;
      if (st1) xp[(size_t)(b1 * 64 + rl) * ldo + 1024 + ic] = q1;
    }
  }
}

extern "C" void kernel_launch(void* const* d_in, const int* in_sizes, int n_in,
                              void* d_out, int out_size, void* d_ws, size_t ws_size,
                              hipStream_t stream) {
  const float* actions   = (const float*)d_in[0];
  const int*   timesteps = (const int*)  d_in[1];
  const int*   cat_ids   = (const int*)  d_in[2];
  const float* W1 = (const float*)d_in[3];
  const float* B1 = (const float*)d_in[4];
  const float* W2 = (const float*)d_in[5];
  const float* B2 = (const float*)d_in[6];
  const float* W3 = (const float*)d_in[7];
  const float* B3 = (const float*)d_in[8];

  short* x = (short*)d_ws;                     // (4096, 2048) bf16 = 16 MiB
  short* h = x + (size_t)64 * 64 * 2048;       // (4096, 1024) bf16 =  8 MiB

  dim3 grid(16, 40), blk(128);

  // GEMM1 (K=64, fp32 A) + fused tau -> x
  gemm_kernel<64, true, false, true, true><<<grid, blk, 0, stream>>>(
      (const void*)actions, 64, W1, B1, cat_ids, (void*)x, 2048, timesteps);
  // GEMM2 (K=2048) + swish -> h
  gemm_kernel<2048, false, true, true, false><<<grid, blk, 0, stream>>>(
      (const void*)x, 2048, W2, B2, cat_ids, (void*)h, 1024, nullptr);
  // GEMM3 (K=1024) -> out (fp32)
  gemm_kernel<1024, false, false, false, false><<<grid, blk, 0, stream>>>(
      (const void*)h, 1024, W3, B3, cat_ids, d_out, 1024, nullptr);
}